// Round 4
// baseline (208.412 us; speedup 1.0000x reference)
//
#include <hip/hip_runtime.h>
#include <hip/hip_cooperative_groups.h>

namespace cg = cooperative_groups;

#define MARGIN 0.3f
#define ANCHOR 0.5f
#define EPS    1e-8f
#define NB     1024      // blocks (4 per CU on 256 CUs -> co-resident)
#define NT     256       // threads per block
#define BJ     256       // j-tile

typedef unsigned long long ull;

__global__ __launch_bounds__(NT, 4) void fused_kernel(
        const float* __restrict__ q, const float* __restrict__ d,
        const float* __restrict__ rates,
        float* __restrict__ sq, float* __restrict__ qual,
        double* __restrict__ psum, unsigned* __restrict__ pcnt,
        float* __restrict__ out, int N, int D) {

    cg::grid_group grid = cg::this_grid();

    const int tid    = threadIdx.x;
    const int lane   = tid & 63;
    const int bid    = blockIdx.x;
    const int nwaves = (NB * NT) >> 6;             // total waves in grid
    const int gwave  = (bid * NT + tid) >> 6;

    // ---------- phase 1: s_q and quality (one wave per row) ----------
    for (int row = gwave; row < N; row += nwaves) {
        const float* r = d + (size_t)row * (size_t)D;
        float dot = 0.f, dn = 0.f, qn = 0.f;
        for (int it = lane * 4; it < D; it += 256) {
            float4 dv = *(const float4*)(r + it);
            float4 qv = *(const float4*)(q + it);
            dot += dv.x*qv.x + dv.y*qv.y + dv.z*qv.z + dv.w*qv.w;
            dn  += dv.x*dv.x + dv.y*dv.y + dv.z*dv.z + dv.w*dv.w;
            qn  += qv.x*qv.x + qv.y*qv.y + qv.z*qv.z + qv.w*qv.w;
        }
        #pragma unroll
        for (int off = 32; off >= 1; off >>= 1) {
            dot += __shfl_xor(dot, off);
            dn  += __shfl_xor(dn,  off);
            qn  += __shfl_xor(qn,  off);
        }
        if (lane == 0) {
            float den = fmaxf(sqrtf(dn) * sqrtf(qn), EPS);
            sq[row]   = dot / den;
            qual[row] = fabsf(rates[row] - ANCHOR);
        }
    }

    grid.sync();

    // ---------- phase 2: N^2 pair partials ----------
    const int IB = (N + NT - 1) / NT;
    const int JB = (N + BJ - 1) / BJ;
    __shared__ float2   tile[BJ];
    __shared__ double   bsum[4];
    __shared__ unsigned bcnt[4];

    for (int t = bid; t < IB * JB; t += NB) {
        int ib = t % IB, jb = t / IB;
        int i  = ib * NT + tid;
        int j0 = jb * BJ;

        __syncthreads();                  // protect tile[] from previous iter
        if (tid < BJ) {
            int j = j0 + tid;
            tile[tid] = make_float2(j < N ? sq[j]   : 0.f,
                                    j < N ? qual[j] : 1e30f);  // never counted
        }
        __syncthreads();

        float my_sq = (i < N) ? sq[i]   : 0.f;
        float my_q  = (i < N) ? qual[i] : -1.f;   // quality >= 0 -> all masked off
        float a     = MARGIN - my_sq;

        float sum = 0.f; unsigned c = 0;
        #pragma unroll 8
        for (int j = 0; j < BJ; ++j) {
            float2 tj = tile[j];
            bool  m = my_q > tj.y;
            float v = fmaxf(a + tj.x, 0.f);
            sum += m ? v : 0.f;
            c   += m ? 1u : 0u;
        }

        #pragma unroll
        for (int off = 32; off >= 1; off >>= 1) {
            sum += __shfl_xor(sum, off);
            c   += __shfl_xor(c,   off);
        }
        int w = tid >> 6;
        if ((tid & 63) == 0) { bsum[w] = (double)sum; bcnt[w] = c; }
        __syncthreads();
        if (tid == 0) {
            psum[t] = bsum[0] + bsum[1] + bsum[2] + bsum[3];
            pcnt[t] = bcnt[0] + bcnt[1] + bcnt[2] + bcnt[3];
        }
    }

    grid.sync();

    // ---------- phase 3: final reduce in block 0 ----------
    if (bid == 0) {
        int nb = IB * JB;
        double s = 0.0; ull c = 0ull;
        for (int k = tid; k < nb; k += NT) { s += psum[k]; c += (ull)pcnt[k]; }
        #pragma unroll
        for (int off = 32; off >= 1; off >>= 1) {
            s += __shfl_xor(s, off);
            c += __shfl_xor(c, off);
        }
        __shared__ double fsum[4];
        __shared__ ull    fcnt[4];
        int w = tid >> 6;
        if ((tid & 63) == 0) { fsum[w] = s; fcnt[w] = c; }
        __syncthreads();
        if (tid == 0) {
            double T = fsum[0] + fsum[1] + fsum[2] + fsum[3];
            ull    C = fcnt[0] + fcnt[1] + fcnt[2] + fcnt[3];
            if (C < 1ull) C = 1ull;
            out[0] = (float)(T / (double)C);
        }
    }
}

extern "C" void kernel_launch(void* const* d_in, const int* in_sizes, int n_in,
                              void* d_out, int out_size, void* d_ws, size_t ws_size,
                              hipStream_t stream) {
    const float* q_emb  = (const float*)d_in[0];
    const float* d_embs = (const float*)d_in[1];
    // d_in[2] = c_emb: computed-but-unused in the reference; skipped.
    const float* rates  = (const float*)d_in[3];

    int N = in_sizes[3];
    int D = in_sizes[0];

    int IB = (N + NT - 1) / NT;
    int JB = (N + BJ - 1) / BJ;
    int nb = IB * JB;

    // ws layout: psum[nb] (8B), pcnt[nb] (4B), sq[N], qual[N]
    double*   psum = (double*)d_ws;
    unsigned* pcnt = (unsigned*)(psum + nb);
    float*    sq   = (float*)(pcnt + nb + (nb & 1));   // keep 8B alignment
    float*    qual = sq + N;
    float*    out  = (float*)d_out;

    void* args[] = { (void*)&q_emb, (void*)&d_embs, (void*)&rates,
                     (void*)&sq, (void*)&qual, (void*)&psum, (void*)&pcnt,
                     (void*)&out, (void*)&N, (void*)&D };
    hipLaunchCooperativeKernel((const void*)fused_kernel,
                               dim3(NB), dim3(NT), args, 0, stream);
}

// Round 5
// 23.745 us; speedup vs baseline: 8.7769x; 8.7769x over previous
//
#include <hip/hip_runtime.h>

#define MARGIN 0.3f
#define ANCHOR 0.5f
#define EPS    1e-8f
#define BJ     256
#define NSLOT  32        // accumulator slots, each on its own 64B line

typedef unsigned long long ull;

// ws accumulator layout (all 64B-padded to avoid same-line serialization):
//   gsum[k] : ws + k*64            (double)
//   gcnt[k] : ws + 2048 + k*64     (unsigned)
//   arr[k]  : ws + 4096 + k*64     (unsigned)
//   master  : ws + 6144            (unsigned)
//   sq[N]   : ws + 8192            (float)
//   qual[N] : sq + N               (float)

// ---------------- kernel 1: s_q, quality, accumulator zero-init ----------------
__global__ __launch_bounds__(256) void sq_kernel(
        const float* __restrict__ q, const float* __restrict__ d,
        const float* __restrict__ rates,
        float* __restrict__ sq, float* __restrict__ qual,
        char* __restrict__ acc, int N, int D) {
    int tid = threadIdx.x;
    if (blockIdx.x == 0) {
        if (tid < NSLOT)              *(double*)  (acc + (size_t)tid * 64)              = 0.0;
        else if (tid < 2 * NSLOT)     *(unsigned*)(acc + 2048 + (size_t)(tid - 32) * 64) = 0u;
        else if (tid < 3 * NSLOT)     *(unsigned*)(acc + 4096 + (size_t)(tid - 64) * 64) = 0u;
        else if (tid == 3 * NSLOT)    *(unsigned*)(acc + 6144)                           = 0u;
    }
    int wave = (blockIdx.x * blockDim.x + tid) >> 6;
    int lane = tid & 63;
    if (wave >= N) return;
    const float* row = d + (size_t)wave * (size_t)D;

    float dot = 0.f, dn = 0.f, qn = 0.f;
    for (int it = lane * 4; it < D; it += 256) {
        float4 dv = *(const float4*)(row + it);
        float4 qv = *(const float4*)(q + it);
        dot += dv.x * qv.x + dv.y * qv.y + dv.z * qv.z + dv.w * qv.w;
        dn  += dv.x * dv.x + dv.y * dv.y + dv.z * dv.z + dv.w * dv.w;
        qn  += qv.x * qv.x + qv.y * qv.y + qv.z * qv.z + qv.w * qv.w;
    }
    #pragma unroll
    for (int off = 32; off >= 1; off >>= 1) {
        dot += __shfl_xor(dot, off);
        dn  += __shfl_xor(dn,  off);
        qn  += __shfl_xor(qn,  off);
    }
    if (lane == 0) {
        float den = fmaxf(sqrtf(dn) * sqrtf(qn), EPS);
        sq[wave]   = dot / den;
        qual[wave] = fabsf(rates[wave] - ANCHOR);
    }
}

// ---------------- kernel 2: N^2 pair partials + fenceless last-block finalize ----
__global__ __launch_bounds__(256) void pair_kernel(
        const float* __restrict__ sq, const float* __restrict__ qual,
        int N, char* __restrict__ acc, float* __restrict__ out, unsigned nblocks) {
    __shared__ float2   tile[BJ];
    __shared__ double   bsum[4];
    __shared__ unsigned bcnt[4];

    int tid = threadIdx.x;
    int i   = blockIdx.x * blockDim.x + tid;
    int j0  = blockIdx.y * BJ;

    if (tid < BJ) {
        int j = j0 + tid;
        tile[tid] = make_float2(j < N ? sq[j]   : 0.f,
                                j < N ? qual[j] : 1e30f);   // never counted
    }
    __syncthreads();

    float my_sq = (i < N) ? sq[i]   : 0.f;
    float my_q  = (i < N) ? qual[i] : -1.f;   // quality >= 0 -> all pairs masked off
    float a     = MARGIN - my_sq;

    float sum = 0.f;
    unsigned c = 0;
    #pragma unroll 8
    for (int j = 0; j < BJ; ++j) {
        float2 t = tile[j];
        bool  m = my_q > t.y;
        float v = fmaxf(a + t.x, 0.f);
        sum += m ? v : 0.f;
        c   += m ? 1u : 0u;
    }

    #pragma unroll
    for (int off = 32; off >= 1; off >>= 1) {
        sum += __shfl_xor(sum, off);
        c   += __shfl_xor(c,   off);
    }
    int w = tid >> 6;
    if ((tid & 63) == 0) { bsum[w] = (double)sum; bcnt[w] = c; }
    __syncthreads();

    if (tid >= 64) return;

    unsigned last = 0;
    if (tid == 0) {
        double   bs = bsum[0] + bsum[1] + bsum[2] + bsum[3];
        unsigned bc = bcnt[0] + bcnt[1] + bcnt[2] + bcnt[3];
        unsigned bid = blockIdx.y * gridDim.x + blockIdx.x;
        unsigned s   = bid & (NSLOT - 1);

        // slot accumulate (distinct 64B lines; <=32 RMWs per line, lines parallel)
        double   old  = atomicAdd((double*)  (acc + (size_t)s * 64), bs);
        unsigned oldc = atomicAdd((unsigned*)(acc + 2048 + (size_t)s * 64), bc);
        // consume returns -> s_waitcnt vmcnt: both RMWs PERFORMED at the
        // device-coherent point before the arrival increment issues.
        asm volatile("" :: "v"(__double2hiint(old)), "v"(__double2loint(old)), "v"(oldc));

        unsigned gsz = (nblocks > s) ? ((nblocks - 1u - s) / NSLOT + 1u) : 0u;
        unsigned pa  = atomicAdd((unsigned*)(acc + 4096 + (size_t)s * 64), 1u);
        if (pa == gsz - 1u) {                       // slot winner
            asm volatile("" :: "v"(pa));
            unsigned nslots = (nblocks < NSLOT) ? nblocks : NSLOT;
            unsigned pm = atomicAdd((unsigned*)(acc + 6144), 1u);
            last = (pm == nslots - 1u) ? 1u : 0u;   // overall last block
        }
    }
    last = __shfl(last, 0);
    if (last) {
        // all slot adds performed; read coherently via atomic RMWs, one wave
        double s = 0.0; ull c2 = 0ull;
        if (tid < NSLOT) {
            s  = atomicAdd((double*)  (acc + (size_t)tid * 64), 0.0);
            c2 = (ull)atomicAdd((unsigned*)(acc + 2048 + (size_t)tid * 64), 0u);
        }
        #pragma unroll
        for (int off = 16; off >= 1; off >>= 1) {   // masks <32: lanes 0..31 reduce
            s  += __shfl_xor(s,  off);
            c2 += __shfl_xor(c2, off);
        }
        if (tid == 0) {
            if (c2 < 1ull) c2 = 1ull;
            out[0] = (float)(s / (double)c2);
        }
    }
}

extern "C" void kernel_launch(void* const* d_in, const int* in_sizes, int n_in,
                              void* d_out, int out_size, void* d_ws, size_t ws_size,
                              hipStream_t stream) {
    const float* q_emb  = (const float*)d_in[0];
    const float* d_embs = (const float*)d_in[1];
    // d_in[2] = c_emb: computed-but-unused in the reference; skipped.
    const float* rates  = (const float*)d_in[3];

    int D = in_sizes[0];
    int N = in_sizes[3];

    char*  acc  = (char*)d_ws;
    float* sq   = (float*)(acc + 8192);
    float* qual = sq + N;
    float* out  = (float*)d_out;

    int rows_per_block = 256 / 64;   // 4 waves/block, 1 row/wave
    sq_kernel<<<(N + rows_per_block - 1) / rows_per_block, 256, 0, stream>>>(
        q_emb, d_embs, rates, sq, qual, acc, N, D);

    dim3 grid((N + 255) / 256, (N + BJ - 1) / BJ);
    pair_kernel<<<grid, 256, 0, stream>>>(sq, qual, N, acc, out,
                                          grid.x * grid.y);
}